// Round 18
// baseline (398.796 us; speedup 1.0000x reference)
//
#include <hip/hip_runtime.h>
#include <math.h>

#define D64 64
#define NBATCH 8
#define CBAND 2.0f
#define CHUNK 128                 // codes per LDS chunk (16 KB)
#define NCHUNK 64                 // K / CHUNK (total)
#define KSPL 4                    // K-split across blockIdx.y
#define NCH0 (NCHUNK / KSPL)      // chunks per split (16)
#define CG 32                     // codes per bm group
#define NGRP 256                  // K / CG

typedef short s16x8 __attribute__((ext_vector_type(8)));   // 8 bf16 (bit pattern)
typedef float f32x4 __attribute__((ext_vector_type(4)));

#define GLOAD16(g, l) __builtin_amdgcn_global_load_lds( \
    (const __attribute__((address_space(1))) unsigned*)(g), \
    (__attribute__((address_space(3))) unsigned*)(l), 16, 0, 0)
#define GLOAD4(g, l) __builtin_amdgcn_global_load_lds( \
    (const __attribute__((address_space(1))) unsigned*)(g), \
    (__attribute__((address_space(3))) unsigned*)(l), 4, 0, 0)

__device__ inline unsigned short f2bf(float f) {
  unsigned u = __builtin_bit_cast(unsigned, f);
  unsigned r = (u + 0x7FFFu + ((u >> 16) & 1u)) >> 16;
  return (unsigned short)r;
}
__device__ inline float bflo(unsigned u) {      // low u16 -> f32
  return __builtin_bit_cast(float, (u & 0xFFFFu) << 16);
}
__device__ inline float bfhi(unsigned u) {      // high u16 -> f32
  return __builtin_bit_cast(float, u & 0xFFFF0000u);
}
// order-preserving float <-> uint (for atomicMin) — validated r5/r15/r16
__device__ inline unsigned pack32(float s) {
  unsigned u = __builtin_bit_cast(unsigned, s);
  return (u & 0x80000000u) ? ~u : (u | 0x80000000u);
}
__device__ inline float unpack32(unsigned u) {
  unsigned b = (u & 0x80000000u) ? (u ^ 0x80000000u) : ~u;
  return __builtin_bit_cast(float, b);
}

// ------- c_sq + (-c_sq/2) + bf16 convert + workspace zeroing -------
__global__ __launch_bounds__(256) void csq_cvt_kernel(
    const float* __restrict__ cb, float* __restrict__ csq,
    float* __restrict__ csqn, short* __restrict__ cbh,
    unsigned int* __restrict__ counts, unsigned* __restrict__ pminu,
    double* __restrict__ sse_parts, int K, int Npts) {
  int t = blockIdx.x * blockDim.x + threadIdx.x;
  if (t < NBATCH * K) counts[t] = 0u;
  if (t < Npts) pminu[t] = 0xFFFFFFFFu;     // packed +inf
  if (t < 256) sse_parts[t] = 0.0;
  int row = t >> 6, lane = t & 63;
  if (row >= K) return;
  float v = cb[(size_t)row * D64 + lane];
  cbh[(size_t)row * D64 + lane] = (short)f2bf(v);
  v *= v;
  #pragma unroll
  for (int off = 32; off; off >>= 1) v += __shfl_xor(v, off, 64);
  if (lane == 0) { csq[row] = v; csqn[row] = -0.5f * v; }
}

// -------- single sweep: per-(point, lane-local 32-code group) min --------
// Swapped MFMA (A=codes, B=z), C init = -csq/2  =>  score = -2*acc.
// 4 POINT-TILES PER WAVE (64 points): the LDS code/csqn reads per i-iter
// now feed 4 MFMAs instead of 2, halving the per-point LDS-read cost that
// bound r16's sweep. bm writes/pack identical to r16 (the 88us version).
__global__ __launch_bounds__(256, 4) void sweep_kernel(
    const float* __restrict__ z, const short* __restrict__ cbh,
    const float* __restrict__ csqn,
    unsigned short* __restrict__ bm, unsigned* __restrict__ pminu,
    int N, int K) {
  __shared__ short lcb[2][CHUNK * D64];     // 2 x 16 KB
  __shared__ float lcsq[2][CHUNK];          // 2 x 512 B  (-csq/2 values)

  int w = threadIdx.x >> 6;
  int l = threadIdx.x & 63;
  int lr = l & 15, lg = l >> 4;
  int base = blockIdx.x * 256 + w * 64;     // 64 points per wave
  int c0g = blockIdx.y * NCH0;              // first global chunk of this split

  s16x8 Z[4][2];
  #pragma unroll
  for (int pt = 0; pt < 4; ++pt) {
    int row = base + pt * 16 + lr;
    #pragma unroll
    for (int kh = 0; kh < 2; ++kh) {
      const float4* zp = reinterpret_cast<const float4*>(
          z + (size_t)row * D64 + kh * 32 + lg * 8);
      float4 p0 = zp[0], p1 = zp[1];
      s16x8 t;
      t[0] = (short)f2bf(p0.x); t[1] = (short)f2bf(p0.y);
      t[2] = (short)f2bf(p0.z); t[3] = (short)f2bf(p0.w);
      t[4] = (short)f2bf(p1.x); t[5] = (short)f2bf(p1.y);
      t[6] = (short)f2bf(p1.z); t[7] = (short)f2bf(p1.w);
      Z[pt][kh] = t;
    }
  }

  int sw = (lr & 7) << 4;
  int p0off = ((lr * 128 + lg * 16) ^ sw);
  int p1off = ((lr * 128 + 64 + lg * 16) ^ sw);
  int swl = (l >> 3) << 4;                  // staging source swizzle

  const char* cbbytes = (const char*)cbh;
#define STAGE(chunk, b)                                                       \
  {                                                                           \
    const char* src = cbbytes + (size_t)(chunk) * (CHUNK * 128);              \
    char* dstb = (char*)lcb[b];                                               \
    _Pragma("unroll")                                                         \
    for (int j = 0; j < 4; ++j) {                                             \
      int X = (w * 4 + j) * 1024 + l * 16;                                    \
      GLOAD16(src + (X ^ swl), dstb + (w * 4 + j) * 1024);                    \
    }                                                                         \
    const char* csrc = (const char*)(csqn + (chunk) * CHUNK) + (w & 1) * 256; \
    GLOAD4(csrc + l * 4, (char*)lcsq[b] + (w & 1) * 256);                     \
  }

  float gm[4];
  #pragma unroll
  for (int pt = 0; pt < 4; ++pt) gm[pt] = -INFINITY;

  auto do_chunk = [&](int cg, int b) {
    const char* pb0 = (const char*)lcb[b] + p0off;
    const char* pb1 = (const char*)lcb[b] + p1off;
    float g[4];
    #pragma unroll
    for (int pt = 0; pt < 4; ++pt) g[pt] = -INFINITY;
    #pragma unroll
    for (int i = 0; i < 8; ++i) {
      s16x8 CA0 = *(const s16x8*)(pb0 + i * 2048);
      s16x8 CA1 = *(const s16x8*)(pb1 + i * 2048);
      float4 cn = *(const float4*)(lcsq[b] + i * 16 + lg * 4);
      #pragma unroll
      for (int pt = 0; pt < 4; ++pt) {
        f32x4 acc = {cn.x, cn.y, cn.z, cn.w};          // C = -csq/2
        acc = __builtin_amdgcn_mfma_f32_16x16x32_bf16(CA0, Z[pt][0], acc, 0, 0, 0);
        acc = __builtin_amdgcn_mfma_f32_16x16x32_bf16(CA1, Z[pt][1], acc, 0, 0, 0);
        float m = fmaxf(fmaxf(acc[0], acc[1]), fmaxf(acc[2], acc[3]));
        g[pt] = fmaxf(g[pt], m);
      }
    }
    // gather the 4 lg values (XOR group {0,16,32,48}), pack + uint2 write
    #pragma unroll
    for (int pt = 0; pt < 4; ++pt) {
      float a = g[pt];
      float bb = __shfl_xor(a, 16, 64);
      float cc2 = __shfl_xor(a, 32, 64);
      float dd = __shfl_xor(a, 48, 64);
      float gmx = fmaxf(fmaxf(a, bb), fmaxf(cc2, dd));  // valid on every lane
      gm[pt] = fmaxf(gm[pt], gmx);
      if (l < 16) {                                     // lg==0: a..dd = lg0..3
        unsigned q0 = (unsigned)f2bf(-2.0f * a) |
                      ((unsigned)f2bf(-2.0f * bb) << 16);
        unsigned q1 = (unsigned)f2bf(-2.0f * cc2) |
                      ((unsigned)f2bf(-2.0f * dd) << 16);
        unsigned short* rp = bm + (size_t)(base + pt * 16 + l) * NGRP + cg * 4;
        *reinterpret_cast<uint2*>(rp) = make_uint2(q0, q1);
      }
    }
  };

  STAGE(c0g, 0);
  __syncthreads();
  for (int c = 0; c < NCH0; ++c) {
    if (c + 1 < NCH0) STAGE(c0g + c + 1, (c + 1) & 1);
    do_chunk(c0g + c, c & 1);
    __syncthreads();
  }
  if (l < 16) {
    // exact: min(score) = -2 * max(acc)
    #pragma unroll
    for (int pt = 0; pt < 4; ++pt)
      atomicMin(&pminu[base + pt * 16 + l], pack32(-2.0f * gm[pt]));
  }
#undef STAGE
}

// ---- wave-per-point rescore: coalesced, 8 codes x 8 dims per round ----
// (verbatim from r16 — passed)
__global__ __launch_bounds__(256) void rescore_wave_kernel(
    const float* __restrict__ z, const float* __restrict__ cb,
    const float* __restrict__ csq, const unsigned short* __restrict__ bm,
    const unsigned* __restrict__ pminu, const int* __restrict__ batch_raw,
    float* __restrict__ out_idx, float* __restrict__ outq,
    unsigned int* __restrict__ counts, double* __restrict__ sse_parts,
    int N, int K) {
  int l = threadIdx.x & 63;
  int n = blockIdx.x * 4 + (threadIdx.x >> 6);

  float thr = unpack32(pminu[n]) + CBAND;
  uint2 u = reinterpret_cast<const uint2*>(bm + (size_t)n * NGRP)[l];
  float v0 = bflo(u.x), v1 = bfhi(u.x), v2 = bflo(u.y), v3 = bfhi(u.y);
  unsigned long long m0 = __ballot(v0 <= thr);
  unsigned long long m1 = __ballot(v1 <= thr);
  unsigned long long m2 = __ballot(v2 <= thr);
  unsigned long long m3 = __ballot(v3 <= thr);

  const float4* z4 = reinterpret_cast<const float4*>(z + (size_t)n * D64);
  float4 zz0 = z4[(l & 7) * 2];
  float4 zz1 = z4[(l & 7) * 2 + 1];

  auto next_group = [&]() -> int {
    if (m0) { int t = __builtin_ctzll(m0); m0 &= m0 - 1; return t * 4 + 0; }
    if (m1) { int t = __builtin_ctzll(m1); m1 &= m1 - 1; return t * 4 + 1; }
    if (m2) { int t = __builtin_ctzll(m2); m2 &= m2 - 1; return t * 4 + 2; }
    if (m3) { int t = __builtin_ctzll(m3); m3 &= m3 - 1; return t * 4 + 3; }
    return -1;
  };

  float b1 = INFINITY, b2 = INFINITY;
  int i1 = 0x7FFFFFFF, i2 = 0x7FFFFFFF;
  bool real = (l & 7) == 0;
  int code_idx = l >> 3;                 // 0..7
  int ioff = code_idx >> 2;              // 0..1
  int sub = code_idx & 3;                // 0..3
  const float4* cbf4 = reinterpret_cast<const float4*>(cb);

  while (m0 | m1 | m2 | m3) {
    int g = next_group();                // wave-uniform
    int cbase = (g >> 2) * 128 + (g & 3) * 4;    // code (i=0, sub=0)
    const float4* gb = cbf4 + (size_t)cbase * 16;
    #pragma unroll
    for (int rr = 0; rr < 4; ++rr) {
      int i = rr * 2 + ioff;
      int rel = (i * 16 + sub) * 16 + (l & 7) * 2;
      float4 q0 = gb[rel];
      float4 q1 = gb[rel + 1];
      float p = q0.x * zz0.x;
      p = fmaf(q0.y, zz0.y, p);
      p = fmaf(q0.z, zz0.z, p);
      p = fmaf(q0.w, zz0.w, p);
      p = fmaf(q1.x, zz1.x, p);
      p = fmaf(q1.y, zz1.y, p);
      p = fmaf(q1.z, zz1.z, p);
      p = fmaf(q1.w, zz1.w, p);
      p += __shfl_xor(p, 1, 64);
      p += __shfl_xor(p, 2, 64);
      p += __shfl_xor(p, 4, 64);
      int k = cbase + i * 16 + sub;
      float s = fmaf(-2.0f, p, csq[k]);
      float sv = real ? s : INFINITY;
      int kv = real ? k : 0x7FFFFFFF;
      bool bet1 = (sv < b1) || (sv == b1 && kv < i1);
      float cs = bet1 ? b1 : sv;  int ci = bet1 ? i1 : kv;
      b1 = bet1 ? sv : b1;        i1 = bet1 ? kv : i1;
      bool bet2 = (cs < b2) || (cs == b2 && ci < i2);
      b2 = bet2 ? cs : b2;        i2 = bet2 ? ci : i2;
    }
  }
  #pragma unroll
  for (int off = 1; off < 64; off <<= 1) {
    float o1 = __shfl_xor(b1, off, 64); int j1 = __shfl_xor(i1, off, 64);
    float o2 = __shfl_xor(b2, off, 64); int j2 = __shfl_xor(i2, off, 64);
    bool t1 = (o1 < b1) || (o1 == b1 && j1 < i1);
    float cs = t1 ? b1 : o1;  int ci = t1 ? i1 : j1;
    b1 = t1 ? o1 : b1;        i1 = t1 ? j1 : i1;
    bool t2 = (cs < b2) || (cs == b2 && ci < i2);
    b2 = t2 ? cs : b2;        i2 = t2 ? ci : i2;
    bool t3 = (o2 < b2) || (o2 == b2 && j2 < i2);
    b2 = t3 ? o2 : b2;        i2 = t3 ? j2 : i2;
  }

  int final_i = i1;
  if (i2 != 0x7FFFFFFF && (b2 - b1) < 1e-3f) {
    double zd = (double)z[(size_t)n * D64 + l];
    double t0 = zd - (double)cb[(size_t)i1 * D64 + l];
    double t1 = zd - (double)cb[(size_t)i2 * D64 + l];
    double d0 = t0 * t0, d1 = t1 * t1;
    #pragma unroll
    for (int off = 1; off < 64; off <<= 1) {
      d0 += __shfl_xor(d0, off, 64);
      d1 += __shfl_xor(d1, off, 64);
    }
    if (d1 < d0 || (d1 == d0 && i2 < i1)) final_i = i2;
  }

  float zl = z[(size_t)n * D64 + l];
  float ql = cb[(size_t)final_i * D64 + l];
  float tl = ql - zl;
  outq[(size_t)n * D64 + l] = zl + tl;
  double loc = (double)tl * tl;
  #pragma unroll
  for (int off = 1; off < 64; off <<= 1) loc += __shfl_xor(loc, off, 64);
  if (l == 0) {
    out_idx[n] = (float)final_i;
    int is64 = (batch_raw[N - 1] == 0) ? 1 : 0;
    int b = is64 ? batch_raw[2 * n] : batch_raw[n];
    atomicAdd(&counts[(size_t)b * K + final_i], 1u);
    atomicAdd(&sse_parts[n & 255], loc);
  }
}

// ---------------- per-batch entropy / perplexity / unique ----------------
__global__ __launch_bounds__(256) void stats_kernel(
    const unsigned int* __restrict__ counts,
    double* __restrict__ perp, double* __restrict__ ent,
    double* __restrict__ uniq, int K) {
  __shared__ double sh4[4], she[4], shu[4];
  int b = blockIdx.x;
  const unsigned int* c = counts + (size_t)b * K;
  int lane = threadIdx.x & 63, w = threadIdx.x >> 6;

  double tot = 0.0;
  for (int k = threadIdx.x; k < K; k += blockDim.x) tot += (double)c[k];
  #pragma unroll
  for (int off = 32; off; off >>= 1) tot += __shfl_xor(tot, off, 64);
  if (lane == 0) sh4[w] = tot;
  __syncthreads();
  double total = sh4[0] + sh4[1] + sh4[2] + sh4[3];
  double denom = fmax(total, 1.0);

  double e = 0.0, u = 0.0;
  for (int k = threadIdx.x; k < K; k += blockDim.x) {
    double cc = (double)c[k];
    double p = cc / denom;
    e -= p * log(p + 1e-10);
    if (cc > 0.0) u += 1.0;
  }
  #pragma unroll
  for (int off = 32; off; off >>= 1) {
    e += __shfl_xor(e, off, 64);
    u += __shfl_xor(u, off, 64);
  }
  if (lane == 0) { she[w] = e; shu[w] = u; }
  __syncthreads();
  if (threadIdx.x == 0) {
    double E = she[0] + she[1] + she[2] + she[3];
    double U = shu[0] + shu[1] + shu[2] + shu[3];
    ent[b] = E; perp[b] = exp(E); uniq[b] = U;
  }
}

// ---------------- finalize scalars ----------------
__global__ void final_kernel(const double* __restrict__ sse_parts,
                             const double* __restrict__ perp,
                             const double* __restrict__ ent,
                             const double* __restrict__ uniq,
                             float* __restrict__ out, int N) {
  int l = threadIdx.x;
  double s = sse_parts[l] + sse_parts[l + 64] +
             sse_parts[l + 128] + sse_parts[l + 192];
  #pragma unroll
  for (int off = 1; off < 64; off <<= 1) s += __shfl_xor(s, off, 64);
  if (l == 0 && blockIdx.x == 0) {
    double mp = 0.0, me = 0.0, mu = 0.0;
    for (int b = 0; b < NBATCH; ++b) { mp += perp[b]; me += ent[b]; mu += uniq[b]; }
    mp /= NBATCH; me /= NBATCH; mu /= NBATCH;
    double loss = s / ((double)N * (double)D64);
    size_t voff = (size_t)N * D64;
    size_t coff = voff + 1;
    size_t poff = coff + 1 + (size_t)N;
    out[voff] = (float)loss;
    out[coff] = (float)loss;
    out[poff] = (float)mp;
    out[poff + 1] = (float)me;
    out[poff + 2] = (float)mu;
  }
}

extern "C" void kernel_launch(void* const* d_in, const int* in_sizes, int n_in,
                              void* d_out, int out_size, void* d_ws, size_t ws_size,
                              hipStream_t stream) {
  const float* z = (const float*)d_in[0];
  const int* bid = (const int*)d_in[1];
  const float* cb = (const float*)d_in[2];
  int N = in_sizes[1];
  int Dd = in_sizes[0] / N;
  int K = in_sizes[2] / Dd;
  float* out = (float*)d_out;

  // workspace layout (256B-aligned chunks); total ~35 MB
  char* ws = (char*)d_ws;
  size_t off = 0;
  auto alloc = [&](size_t bytes) {
    void* p = ws + off;
    off += (bytes + 255) & ~(size_t)255;
    return p;
  };
  unsigned int* counts = (unsigned int*)alloc((size_t)NBATCH * K * 4);
  double* sse_parts = (double*)alloc(256 * 8);
  double* perp = (double*)alloc(8 * NBATCH);
  double* ent  = (double*)alloc(8 * NBATCH);
  double* uniq = (double*)alloc(8 * NBATCH);
  float* csq = (float*)alloc((size_t)K * 4);
  float* csqn = (float*)alloc((size_t)K * 4);
  short* cbh = (short*)alloc((size_t)K * D64 * 2);
  unsigned* pminu = (unsigned*)alloc((size_t)N * 4);
  unsigned short* bm = (unsigned short*)alloc((size_t)N * NGRP * 2);

  size_t ioff = (size_t)N * Dd + 2;

  csq_cvt_kernel<<<(K * 64 + 255) / 256, 256, 0, stream>>>(
      cb, csq, csqn, cbh, counts, pminu, sse_parts, K, N);
  dim3 sg(N / 256, KSPL);
  sweep_kernel<<<sg, 256, 0, stream>>>(z, cbh, csqn, bm, pminu, N, K);
  rescore_wave_kernel<<<N / 4, 256, 0, stream>>>(
      z, cb, csq, bm, pminu, bid, out + ioff, out, counts, sse_parts, N, K);
  stats_kernel<<<NBATCH, 256, 0, stream>>>(counts, perp, ent, uniq, K);
  final_kernel<<<1, 64, 0, stream>>>(sse_parts, perp, ent, uniq, out, N);
}

// Round 19
// 183.264 us; speedup vs baseline: 2.1761x; 2.1761x over previous
//
#include <hip/hip_runtime.h>
#include <math.h>

#define D64 64
#define NBATCH 8
#define CBAND 2.0f
#define CHUNK 128                 // codes per LDS chunk (16 KB)
#define NCHUNK 64                 // K / CHUNK (total)
#define KSPL 2                    // K-split across blockIdx.y
#define NCH0 (NCHUNK / KSPL)      // chunks per split (32)
#define CG 32                     // codes per bm group
#define NGRP 256                  // K / CG

typedef short s16x8 __attribute__((ext_vector_type(8)));   // 8 bf16 (bit pattern)
typedef float f32x4 __attribute__((ext_vector_type(4)));

#define GLOAD16(g, l) __builtin_amdgcn_global_load_lds( \
    (const __attribute__((address_space(1))) unsigned*)(g), \
    (__attribute__((address_space(3))) unsigned*)(l), 16, 0, 0)
#define GLOAD4(g, l) __builtin_amdgcn_global_load_lds( \
    (const __attribute__((address_space(1))) unsigned*)(g), \
    (__attribute__((address_space(3))) unsigned*)(l), 4, 0, 0)

__device__ inline unsigned short f2bf(float f) {
  unsigned u = __builtin_bit_cast(unsigned, f);
  unsigned r = (u + 0x7FFFu + ((u >> 16) & 1u)) >> 16;
  return (unsigned short)r;
}
__device__ inline float bflo(unsigned u) {      // low u16 -> f32
  return __builtin_bit_cast(float, (u & 0xFFFFu) << 16);
}
__device__ inline float bfhi(unsigned u) {      // high u16 -> f32
  return __builtin_bit_cast(float, u & 0xFFFF0000u);
}
// order-preserving float <-> uint (for atomicMin) — validated r5/r15/r16
__device__ inline unsigned pack32(float s) {
  unsigned u = __builtin_bit_cast(unsigned, s);
  return (u & 0x80000000u) ? ~u : (u | 0x80000000u);
}
__device__ inline float unpack32(unsigned u) {
  unsigned b = (u & 0x80000000u) ? (u ^ 0x80000000u) : ~u;
  return __builtin_bit_cast(float, b);
}

// ------- c_sq + (-c_sq/2) + bf16 convert + workspace zeroing -------
__global__ __launch_bounds__(256) void csq_cvt_kernel(
    const float* __restrict__ cb, float* __restrict__ csq,
    float* __restrict__ csqn, short* __restrict__ cbh,
    unsigned int* __restrict__ counts, unsigned* __restrict__ pminu,
    double* __restrict__ sse_parts, double* __restrict__ ent,
    double* __restrict__ uniq, int K, int Npts) {
  int t = blockIdx.x * blockDim.x + threadIdx.x;
  if (t < NBATCH * K) counts[t] = 0u;
  if (t < Npts) pminu[t] = 0xFFFFFFFFu;     // packed +inf
  if (t < 256) sse_parts[t] = 0.0;
  if (t < NBATCH) { ent[t] = 0.0; uniq[t] = 0.0; }
  int row = t >> 6, lane = t & 63;
  if (row >= K) return;
  float v = cb[(size_t)row * D64 + lane];
  cbh[(size_t)row * D64 + lane] = (short)f2bf(v);
  v *= v;
  #pragma unroll
  for (int off = 32; off; off >>= 1) v += __shfl_xor(v, off, 64);
  if (lane == 0) { csq[row] = v; csqn[row] = -0.5f * v; }
}

// -------- single sweep: per-(point, lane-local 32-code group) min --------
// (verbatim from r16 — the 189us/88us passing version)
__global__ __launch_bounds__(256, 4) void sweep_kernel(
    const float* __restrict__ z, const short* __restrict__ cbh,
    const float* __restrict__ csqn,
    unsigned short* __restrict__ bm, unsigned* __restrict__ pminu,
    int N, int K) {
  __shared__ short lcb[2][CHUNK * D64];     // 2 x 16 KB
  __shared__ float lcsq[2][CHUNK];          // 2 x 512 B  (-csq/2 values)

  int w = threadIdx.x >> 6;
  int l = threadIdx.x & 63;
  int lr = l & 15, lg = l >> 4;
  int base = blockIdx.x * 128 + w * 32;
  int c0g = blockIdx.y * NCH0;              // first global chunk of this split

  s16x8 Z[2][2];
  #pragma unroll
  for (int pt = 0; pt < 2; ++pt) {
    int row = base + pt * 16 + lr;
    #pragma unroll
    for (int kh = 0; kh < 2; ++kh) {
      const float4* zp = reinterpret_cast<const float4*>(
          z + (size_t)row * D64 + kh * 32 + lg * 8);
      float4 p0 = zp[0], p1 = zp[1];
      s16x8 t;
      t[0] = (short)f2bf(p0.x); t[1] = (short)f2bf(p0.y);
      t[2] = (short)f2bf(p0.z); t[3] = (short)f2bf(p0.w);
      t[4] = (short)f2bf(p1.x); t[5] = (short)f2bf(p1.y);
      t[6] = (short)f2bf(p1.z); t[7] = (short)f2bf(p1.w);
      Z[pt][kh] = t;
    }
  }

  int sw = (lr & 7) << 4;
  int p0off = ((lr * 128 + lg * 16) ^ sw);
  int p1off = ((lr * 128 + 64 + lg * 16) ^ sw);
  int swl = (l >> 3) << 4;                  // staging source swizzle

  const char* cbbytes = (const char*)cbh;
#define STAGE(chunk, b)                                                       \
  {                                                                           \
    const char* src = cbbytes + (size_t)(chunk) * (CHUNK * 128);              \
    char* dstb = (char*)lcb[b];                                               \
    _Pragma("unroll")                                                         \
    for (int j = 0; j < 4; ++j) {                                             \
      int X = (w * 4 + j) * 1024 + l * 16;                                    \
      GLOAD16(src + (X ^ swl), dstb + (w * 4 + j) * 1024);                    \
    }                                                                         \
    const char* csrc = (const char*)(csqn + (chunk) * CHUNK) + (w & 1) * 256; \
    GLOAD4(csrc + l * 4, (char*)lcsq[b] + (w & 1) * 256);                     \
  }

  float gm0 = -INFINITY, gm1 = -INFINITY;   // running MAX of acc (exact)

  auto do_chunk = [&](int cg, int b) {
    const char* pb0 = (const char*)lcb[b] + p0off;
    const char* pb1 = (const char*)lcb[b] + p1off;
    float g0 = -INFINITY, g1 = -INFINITY;   // per-lane group max (pt0, pt1)
    #pragma unroll
    for (int i = 0; i < 8; ++i) {
      s16x8 CA0 = *(const s16x8*)(pb0 + i * 2048);
      s16x8 CA1 = *(const s16x8*)(pb1 + i * 2048);
      float4 cn = *(const float4*)(lcsq[b] + i * 16 + lg * 4);
      #pragma unroll
      for (int pt = 0; pt < 2; ++pt) {
        f32x4 acc = {cn.x, cn.y, cn.z, cn.w};          // C = -csq/2
        acc = __builtin_amdgcn_mfma_f32_16x16x32_bf16(CA0, Z[pt][0], acc, 0, 0, 0);
        acc = __builtin_amdgcn_mfma_f32_16x16x32_bf16(CA1, Z[pt][1], acc, 0, 0, 0);
        float m = fmaxf(fmaxf(acc[0], acc[1]), fmaxf(acc[2], acc[3]));
        if (pt == 0) g0 = fmaxf(g0, m); else g1 = fmaxf(g1, m);
      }
    }
    // gather the 4 lg values (XOR group {0,16,32,48}), pack + uint2 write
    #pragma unroll
    for (int pt = 0; pt < 2; ++pt) {
      float a = pt ? g1 : g0;
      float bb = __shfl_xor(a, 16, 64);
      float cc2 = __shfl_xor(a, 32, 64);
      float dd = __shfl_xor(a, 48, 64);
      float gmx = fmaxf(fmaxf(a, bb), fmaxf(cc2, dd)); // valid on every lane
      if (pt == 0) gm0 = fmaxf(gm0, gmx); else gm1 = fmaxf(gm1, gmx);
      if (l < 16) {                                    // lg==0: a..dd = lg0..3
        unsigned q0 = (unsigned)f2bf(-2.0f * a) |
                      ((unsigned)f2bf(-2.0f * bb) << 16);
        unsigned q1 = (unsigned)f2bf(-2.0f * cc2) |
                      ((unsigned)f2bf(-2.0f * dd) << 16);
        unsigned short* rp = bm + (size_t)(base + pt * 16 + l) * NGRP + cg * 4;
        *reinterpret_cast<uint2*>(rp) = make_uint2(q0, q1);
      }
    }
  };

  STAGE(c0g, 0);
  __syncthreads();
  for (int c = 0; c < NCH0; ++c) {
    if (c + 1 < NCH0) STAGE(c0g + c + 1, (c + 1) & 1);
    do_chunk(c0g + c, c & 1);
    __syncthreads();
  }
  if (l < 16) {
    // exact: min(score) = -2 * max(acc)
    atomicMin(&pminu[base + l], pack32(-2.0f * gm0));
    atomicMin(&pminu[base + 16 + l], pack32(-2.0f * gm1));
  }
#undef STAGE
}

// ---- wave-per-point rescore: coalesced, 8 codes x 8 dims per round ----
// (verbatim from r16 — passed)
__global__ __launch_bounds__(256) void rescore_wave_kernel(
    const float* __restrict__ z, const float* __restrict__ cb,
    const float* __restrict__ csq, const unsigned short* __restrict__ bm,
    const unsigned* __restrict__ pminu, const int* __restrict__ batch_raw,
    float* __restrict__ out_idx, float* __restrict__ outq,
    unsigned int* __restrict__ counts, double* __restrict__ sse_parts,
    int N, int K) {
  int l = threadIdx.x & 63;
  int n = blockIdx.x * 4 + (threadIdx.x >> 6);

  float thr = unpack32(pminu[n]) + CBAND;
  uint2 u = reinterpret_cast<const uint2*>(bm + (size_t)n * NGRP)[l];
  float v0 = bflo(u.x), v1 = bfhi(u.x), v2 = bflo(u.y), v3 = bfhi(u.y);
  unsigned long long m0 = __ballot(v0 <= thr);
  unsigned long long m1 = __ballot(v1 <= thr);
  unsigned long long m2 = __ballot(v2 <= thr);
  unsigned long long m3 = __ballot(v3 <= thr);

  const float4* z4 = reinterpret_cast<const float4*>(z + (size_t)n * D64);
  float4 zz0 = z4[(l & 7) * 2];
  float4 zz1 = z4[(l & 7) * 2 + 1];

  auto next_group = [&]() -> int {
    if (m0) { int t = __builtin_ctzll(m0); m0 &= m0 - 1; return t * 4 + 0; }
    if (m1) { int t = __builtin_ctzll(m1); m1 &= m1 - 1; return t * 4 + 1; }
    if (m2) { int t = __builtin_ctzll(m2); m2 &= m2 - 1; return t * 4 + 2; }
    if (m3) { int t = __builtin_ctzll(m3); m3 &= m3 - 1; return t * 4 + 3; }
    return -1;
  };

  float b1 = INFINITY, b2 = INFINITY;
  int i1 = 0x7FFFFFFF, i2 = 0x7FFFFFFF;
  bool real = (l & 7) == 0;
  int code_idx = l >> 3;                 // 0..7
  int ioff = code_idx >> 2;              // 0..1
  int sub = code_idx & 3;                // 0..3
  const float4* cbf4 = reinterpret_cast<const float4*>(cb);

  while (m0 | m1 | m2 | m3) {
    int g = next_group();                // wave-uniform
    int cbase = (g >> 2) * 128 + (g & 3) * 4;    // code (i=0, sub=0)
    const float4* gb = cbf4 + (size_t)cbase * 16;
    #pragma unroll
    for (int rr = 0; rr < 4; ++rr) {
      int i = rr * 2 + ioff;
      int rel = (i * 16 + sub) * 16 + (l & 7) * 2;
      float4 q0 = gb[rel];
      float4 q1 = gb[rel + 1];
      float p = q0.x * zz0.x;
      p = fmaf(q0.y, zz0.y, p);
      p = fmaf(q0.z, zz0.z, p);
      p = fmaf(q0.w, zz0.w, p);
      p = fmaf(q1.x, zz1.x, p);
      p = fmaf(q1.y, zz1.y, p);
      p = fmaf(q1.z, zz1.z, p);
      p = fmaf(q1.w, zz1.w, p);
      p += __shfl_xor(p, 1, 64);
      p += __shfl_xor(p, 2, 64);
      p += __shfl_xor(p, 4, 64);
      int k = cbase + i * 16 + sub;
      float s = fmaf(-2.0f, p, csq[k]);
      float sv = real ? s : INFINITY;
      int kv = real ? k : 0x7FFFFFFF;
      bool bet1 = (sv < b1) || (sv == b1 && kv < i1);
      float cs = bet1 ? b1 : sv;  int ci = bet1 ? i1 : kv;
      b1 = bet1 ? sv : b1;        i1 = bet1 ? kv : i1;
      bool bet2 = (cs < b2) || (cs == b2 && ci < i2);
      b2 = bet2 ? cs : b2;        i2 = bet2 ? ci : i2;
    }
  }
  #pragma unroll
  for (int off = 1; off < 64; off <<= 1) {
    float o1 = __shfl_xor(b1, off, 64); int j1 = __shfl_xor(i1, off, 64);
    float o2 = __shfl_xor(b2, off, 64); int j2 = __shfl_xor(i2, off, 64);
    bool t1 = (o1 < b1) || (o1 == b1 && j1 < i1);
    float cs = t1 ? b1 : o1;  int ci = t1 ? i1 : j1;
    b1 = t1 ? o1 : b1;        i1 = t1 ? j1 : i1;
    bool t2 = (cs < b2) || (cs == b2 && ci < i2);
    b2 = t2 ? cs : b2;        i2 = t2 ? ci : i2;
    bool t3 = (o2 < b2) || (o2 == b2 && j2 < i2);
    b2 = t3 ? o2 : b2;        i2 = t3 ? j2 : i2;
  }

  int final_i = i1;
  if (i2 != 0x7FFFFFFF && (b2 - b1) < 1e-3f) {
    double zd = (double)z[(size_t)n * D64 + l];
    double t0 = zd - (double)cb[(size_t)i1 * D64 + l];
    double t1 = zd - (double)cb[(size_t)i2 * D64 + l];
    double d0 = t0 * t0, d1 = t1 * t1;
    #pragma unroll
    for (int off = 1; off < 64; off <<= 1) {
      d0 += __shfl_xor(d0, off, 64);
      d1 += __shfl_xor(d1, off, 64);
    }
    if (d1 < d0 || (d1 == d0 && i2 < i1)) final_i = i2;
  }

  float zl = z[(size_t)n * D64 + l];
  float ql = cb[(size_t)final_i * D64 + l];
  float tl = ql - zl;
  outq[(size_t)n * D64 + l] = zl + tl;
  double loc = (double)tl * tl;
  #pragma unroll
  for (int off = 1; off < 64; off <<= 1) loc += __shfl_xor(loc, off, 64);
  if (l == 0) {
    out_idx[n] = (float)final_i;
    int is64 = (batch_raw[N - 1] == 0) ? 1 : 0;
    int b = is64 ? batch_raw[2 * n] : batch_raw[n];
    atomicAdd(&counts[(size_t)b * K + final_i], 1u);
    atomicAdd(&sse_parts[n & 255], loc);
  }
}

// ---------------- per-batch counts total (8 blocks) ----------------
__global__ __launch_bounds__(256) void totals_kernel(
    const unsigned int* __restrict__ counts, double* __restrict__ totals,
    int K) {
  __shared__ double sh4[4];
  int b = blockIdx.x;
  const unsigned int* c = counts + (size_t)b * K;
  int lane = threadIdx.x & 63, w = threadIdx.x >> 6;
  double tot = 0.0;
  for (int k = threadIdx.x; k < K; k += blockDim.x) tot += (double)c[k];
  #pragma unroll
  for (int off = 32; off; off >>= 1) tot += __shfl_xor(tot, off, 64);
  if (lane == 0) sh4[w] = tot;
  __syncthreads();
  if (threadIdx.x == 0)
    totals[b] = sh4[0] + sh4[1] + sh4[2] + sh4[3];
}

// ------- per-batch entropy / unique partials (8 x 8 = 64 blocks) -------
__global__ __launch_bounds__(256) void stats_partial_kernel(
    const unsigned int* __restrict__ counts, const double* __restrict__ totals,
    double* __restrict__ ent, double* __restrict__ uniq, int K) {
  __shared__ double she[4], shu[4];
  int b = blockIdx.x;
  int s = blockIdx.y;
  int kslice = K / 8;
  const unsigned int* c = counts + (size_t)b * K + s * kslice;
  int lane = threadIdx.x & 63, w = threadIdx.x >> 6;
  double denom = fmax(totals[b], 1.0);

  double e = 0.0, u = 0.0;
  for (int k = threadIdx.x; k < kslice; k += blockDim.x) {
    double cc = (double)c[k];
    double p = cc / denom;
    e -= p * log(p + 1e-10);
    if (cc > 0.0) u += 1.0;
  }
  #pragma unroll
  for (int off = 32; off; off >>= 1) {
    e += __shfl_xor(e, off, 64);
    u += __shfl_xor(u, off, 64);
  }
  if (lane == 0) { she[w] = e; shu[w] = u; }
  __syncthreads();
  if (threadIdx.x == 0) {
    atomicAdd(&ent[b], she[0] + she[1] + she[2] + she[3]);
    atomicAdd(&uniq[b], shu[0] + shu[1] + shu[2] + shu[3]);
  }
}

// ---------------- finalize scalars ----------------
__global__ void final_kernel(const double* __restrict__ sse_parts,
                             const double* __restrict__ ent,
                             const double* __restrict__ uniq,
                             float* __restrict__ out, int N) {
  int l = threadIdx.x;
  double s = sse_parts[l] + sse_parts[l + 64] +
             sse_parts[l + 128] + sse_parts[l + 192];
  #pragma unroll
  for (int off = 1; off < 64; off <<= 1) s += __shfl_xor(s, off, 64);
  if (l == 0 && blockIdx.x == 0) {
    double mp = 0.0, me = 0.0, mu = 0.0;
    for (int b = 0; b < NBATCH; ++b) {
      double E = ent[b];
      mp += exp(E); me += E; mu += uniq[b];
    }
    mp /= NBATCH; me /= NBATCH; mu /= NBATCH;
    double loss = s / ((double)N * (double)D64);
    size_t voff = (size_t)N * D64;
    size_t coff = voff + 1;
    size_t poff = coff + 1 + (size_t)N;
    out[voff] = (float)loss;
    out[coff] = (float)loss;
    out[poff] = (float)mp;
    out[poff + 1] = (float)me;
    out[poff + 2] = (float)mu;
  }
}

extern "C" void kernel_launch(void* const* d_in, const int* in_sizes, int n_in,
                              void* d_out, int out_size, void* d_ws, size_t ws_size,
                              hipStream_t stream) {
  const float* z = (const float*)d_in[0];
  const int* bid = (const int*)d_in[1];
  const float* cb = (const float*)d_in[2];
  int N = in_sizes[1];
  int Dd = in_sizes[0] / N;
  int K = in_sizes[2] / Dd;
  float* out = (float*)d_out;

  // workspace layout (256B-aligned chunks); total ~35 MB
  char* ws = (char*)d_ws;
  size_t off = 0;
  auto alloc = [&](size_t bytes) {
    void* p = ws + off;
    off += (bytes + 255) & ~(size_t)255;
    return p;
  };
  unsigned int* counts = (unsigned int*)alloc((size_t)NBATCH * K * 4);
  double* sse_parts = (double*)alloc(256 * 8);
  double* totals = (double*)alloc(8 * NBATCH);
  double* ent  = (double*)alloc(8 * NBATCH);
  double* uniq = (double*)alloc(8 * NBATCH);
  float* csq = (float*)alloc((size_t)K * 4);
  float* csqn = (float*)alloc((size_t)K * 4);
  short* cbh = (short*)alloc((size_t)K * D64 * 2);
  unsigned* pminu = (unsigned*)alloc((size_t)N * 4);
  unsigned short* bm = (unsigned short*)alloc((size_t)N * NGRP * 2);

  size_t ioff = (size_t)N * Dd + 2;

  csq_cvt_kernel<<<(K * 64 + 255) / 256, 256, 0, stream>>>(
      cb, csq, csqn, cbh, counts, pminu, sse_parts, ent, uniq, K, N);
  dim3 sg(N / 128, KSPL);
  sweep_kernel<<<sg, 256, 0, stream>>>(z, cbh, csqn, bm, pminu, N, K);
  rescore_wave_kernel<<<N / 4, 256, 0, stream>>>(
      z, cb, csq, bm, pminu, bid, out + ioff, out, counts, sse_parts, N, K);
  totals_kernel<<<NBATCH, 256, 0, stream>>>(counts, totals, K);
  dim3 stg(NBATCH, 8);
  stats_partial_kernel<<<stg, 256, 0, stream>>>(counts, totals, ent, uniq, K);
  final_kernel<<<1, 64, 0, stream>>>(sse_parts, ent, uniq, out, N);
}